// Round 10
// baseline (60.576 us; speedup 1.0000x reference)
//
#include <hip/hip_runtime.h>
#include <hip/hip_bf16.h>

#define BB   16
#define EMB  768
#define CIN  64
#define COUT 64
#define HH   112
#define WW   112
#define HID  192
#define TOTAL 36864                 // COUT*CIN*9
#define KSZ  576                    // CIN*9
#define PW   114                    // padded H/W
#define CELL 128                    // bytes per (row,col) cell: 64 ci * 2B
#define ROWB (PW * CELL)            // 14592 B per padded row

typedef short bf16x8 __attribute__((ext_vector_type(8)));
typedef float f32x4  __attribute__((ext_vector_type(4)));
typedef int   i32x4  __attribute__((ext_vector_type(4)));

static __device__ __forceinline__ unsigned short f2bf(float f) {
    unsigned u = __float_as_uint(f);
    u += 0x7FFF + ((u >> 16) & 1);          // RNE
    return (unsigned short)(u >> 16);
}

static __device__ __forceinline__ bf16x8 pack8(const float* v) {
    bf16x8 r;
    #pragma unroll
    for (int j = 0; j < 8; ++j) r[j] = (short)f2bf(v[j]);
    return r;
}

#define GLOAD_LDS16(g, l) \
    __builtin_amdgcn_global_load_lds((const __attribute__((address_space(1))) void*)(g), \
                                     (__attribute__((address_space(3))) void*)(l), 16, 0, 0)

// ---- K1: prepass (blocks 0..1823) + mlp1 (blocks 1824..2015) ----
// prepass v2: feat NCHW fp32 -> padded NHWC bf16 P, in-register transpose, no LDS.
// thread = (ci-octet o, px-quad q): 8 coalesced f32x4 plane loads -> 4 x 16B writes.
__global__ __launch_bounds__(256) void pre_mlp1(const float* __restrict__ feat,
                                                unsigned short* __restrict__ P,
                                                const float* __restrict__ cls,
                                                const float* __restrict__ W1,
                                                const float* __restrict__ b1,
                                                float* __restrict__ h) {
    __shared__ float smem[EMB + 16 * 17];
    const int bid = blockIdx.x;
    const int tid = threadIdx.x;

    if (bid < HH * BB) {
        // ---------------- prepass data row ----------------
        const int b = bid & 15;
        const int y = bid >> 4;                 // image row 0..111
        unsigned short* Prow = P + ((size_t)b * PW + y + 1) * (PW * 64);
        if (tid < 16) {                         // zero x-halo cells 0 and 113
            const int cell = (tid >> 3) ? (PW - 1) : 0;
            *(i32x4*)((char*)Prow + cell * CELL + (tid & 7) * 16) = (i32x4){0, 0, 0, 0};
        }
        const int o = tid >> 5;                 // ci octet 0..7
        const int q = tid & 31;                 // px quad, active < 28
        if (q < 28) {
            const float* fb = feat + (((size_t)b * CIN + o * 8) * HH + y) * WW + 4 * q;
            f32x4 v[8];
            #pragma unroll
            for (int j = 0; j < 8; ++j) v[j] = *(const f32x4*)(fb + (size_t)j * (HH * WW));
            #pragma unroll
            for (int i = 0; i < 4; ++i) {
                unsigned short w[8];
                #pragma unroll
                for (int j = 0; j < 8; ++j) w[j] = f2bf(v[j][i]);
                *(bf16x8*)(Prow + (size_t)(4 * q + i + 1) * 64 + o * 8) = *(bf16x8*)w;
            }
        }
    } else if (bid < HH * BB + 32) {
        // ---------------- prepass halo rows (py = 0, 113) ----------------
        const int idx = bid - HH * BB;
        const int b = idx & 15;
        unsigned short* Prow = P + ((size_t)b * PW + ((idx >> 4) ? (PW - 1) : 0)) * (PW * 64);
        #pragma unroll
        for (int k = 0; k < 4; ++k) {
            const int i = tid + 256 * k;
            if (i < 912) ((i32x4*)Prow)[i] = (i32x4){0, 0, 0, 0};
        }
    } else {
        // ---------------- mlp1: h = relu(cls @ W1 + b1) ----------------
        float* xs  = smem;                      // 768
        float* red = smem + EMB;                // 16 x 17
        const int idx = bid - (HH * BB + 32);   // 0..191
        const int b   = idx / 12;
        const int jg  = idx - 12 * b;
        for (int i = tid; i < EMB; i += 256) xs[i] = cls[b * EMB + i];
        __syncthreads();
        const int j16 = tid & 15;
        const int kq  = tid >> 4;
        const int j   = jg * 16 + j16;
        float acc = 0.f;
        #pragma unroll
        for (int k = kq * 48; k < kq * 48 + 48; ++k) acc += xs[k] * W1[k * HID + j];
        red[j16 * 17 + kq] = acc;
        __syncthreads();
        if (tid < 16) {
            float s = b1[jg * 16 + tid];
            #pragma unroll
            for (int q = 0; q < 16; ++q) s += red[tid * 17 + q];
            h[b * HID + jg * 16 + tid] = fmaxf(s, 0.f);
        }
    }
}

// ---- K2: MFMA GEMM  params = tanh(h @ W2 + b2) (+ identity at center tap),
//      bf16 out as A[b][p9][co][ci].  M=16(b), K=192, N=36864. ----
__global__ __launch_bounds__(256) void mlp2_kernel(const float* __restrict__ h,
                                                   const float* __restrict__ W2,
                                                   const float* __restrict__ b2,
                                                   unsigned short* __restrict__ Ag) {
    __shared__ float hs[16 * 193];
    const int tid = threadIdx.x;
    for (int i = tid; i < BB * HID; i += 256) {
        const int bb = i / HID;
        hs[bb * 193 + (i - bb * HID)] = h[i];
    }
    __syncthreads();
    const int wave = tid >> 6;
    const int lane = tid & 63;
    const int lg   = lane >> 4;
    const int ln   = lane & 15;
    const int t0   = (blockIdx.x * 4 + wave) * 16;

    bf16x8 a6[6];
    #pragma unroll
    for (int kk = 0; kk < 6; ++kk) {
        float v[8];
        #pragma unroll
        for (int j = 0; j < 8; ++j) v[j] = hs[ln * 193 + kk * 32 + lg * 8 + j];
        a6[kk] = pack8(v);
    }

    f32x4 acc = (f32x4){0.f, 0.f, 0.f, 0.f};
    #pragma unroll
    for (int kk = 0; kk < 6; ++kk) {
        float w[8];
        #pragma unroll
        for (int j = 0; j < 8; ++j)
            w[j] = W2[(size_t)(kk * 32 + lg * 8 + j) * TOTAL + t0 + ln];
        acc = __builtin_amdgcn_mfma_f32_16x16x32_bf16(a6[kk], pack8(w), acc, 0, 0, 0);
    }

    const int t    = t0 + ln;
    const float bias = b2[t];
    const int co  = t / KSZ;
    const int rem = t - co * KSZ;
    const int ci  = rem / 9;
    const int p9  = rem - ci * 9;
    const float idv = (p9 == 4 && co == ci) ? 1.f : 0.f;
    unsigned short* pA = Ag + (size_t)(p9 * 64 + co) * 64 + ci;
    #pragma unroll
    for (int rg = 0; rg < 4; ++rg) {
        const int bi = lg * 4 + rg;
        pA[(size_t)bi * TOTAL] = f2bf(tanhf(acc[rg] + bias) + idv);
    }
}

// -------- K3: conv MFMA implicit GEMM, gload_lds staged from P (r4-proven body) --------
// Block: 256 thr / 4 waves; wave = (co-half cog, out-row r). 64 co x 2 rows x 112 px.
// LDS: 4 padded rows [s][cell 0..113][64ci], chunk swizzle g' = g ^ (cell&7) applied
// on the gload_lds SOURCE (LDS dest linear); reads undo it.
__global__ __launch_bounds__(256) void conv_kernel(const unsigned short* __restrict__ Ag,
                                                   const unsigned short* __restrict__ P,
                                                   float* __restrict__ out) {
    __shared__ __align__(16) char lds[4 * ROWB];    // 58368 B
    const int tid = threadIdx.x;
    // XCD-chunked swizzle: each XCD owns 112 consecutive logical blocks (= 2 batches)
    const int bid  = (blockIdx.x & 7) * 112 + (blockIdx.x >> 3);
    const int b    = bid / 56;
    const int tile = bid - b * 56;
    const int y0   = tile * 2;

    // stage padded rows y0..y0+3 via global_load_lds, inverse-swizzled source
    const char* Prow0 = (const char*)(P + ((size_t)b * PW + y0) * (PW * 64));
    #pragma unroll
    for (int it = 0; it < 14; ++it) {
        const int i = it * 256 + tid;               // chunk 0..3583
        const int s = i / 912;
        const int j = i - s * 912;
        const int c = j >> 3, g = j & 7;
        GLOAD_LDS16(Prow0 + (size_t)s * ROWB + c * CELL + ((g ^ (c & 7)) << 4),
                    lds + (size_t)i * 16);
    }
    if (tid < 64) {                                 // chunks 3584..3647
        const int i = 3584 + tid;
        const int j = i - 3 * 912;
        const int c = j >> 3, g = j & 7;
        GLOAD_LDS16(Prow0 + (size_t)3 * ROWB + c * CELL + ((g ^ (c & 7)) << 4),
                    lds + (size_t)i * 16);
    }

    // A-fragments for this wave's 32 co x 9 taps x 64 ci, fully preloaded
    const int wave = tid >> 6;
    const int lane = tid & 63;
    const int cog  = wave & 1;
    const int r    = wave >> 1;
    const int lg   = lane >> 4;
    const int ln   = lane & 15;
    const unsigned short* Ab = Ag + (size_t)b * 9 * 4096;
    bf16x8 af[9][2][2];
    #pragma unroll
    for (int p9 = 0; p9 < 9; ++p9)
        #pragma unroll
        for (int ct = 0; ct < 2; ++ct)
            #pragma unroll
            for (int cib = 0; cib < 2; ++cib)
                af[p9][ct][cib] = *(const bf16x8*)(Ab + (size_t)(p9 * 64 + cog * 32 + ct * 16 + ln) * 64
                                                   + cib * 32 + lg * 8);
    __syncthreads();

    f32x4 acc[2][7];
    #pragma unroll
    for (int ct = 0; ct < 2; ++ct)
        #pragma unroll
        for (int t = 0; t < 7; ++t) acc[ct][t] = (f32x4){0.f, 0.f, 0.f, 0.f};

    #pragma unroll
    for (int p9 = 0; p9 < 9; ++p9) {
        const int kh = p9 / 3, kw = p9 - 3 * kh;
        const char* lbase = lds + (r + kh) * ROWB + (ln + kw) * CELL;
        const int   c7    = (ln + kw) & 7;
        #pragma unroll
        for (int cib = 0; cib < 2; ++cib) {
            const int sw = ((cib * 4 + lg) ^ c7) << 4;
            #pragma unroll
            for (int t = 0; t < 7; ++t) {
                const bf16x8 bf = *(const bf16x8*)(lbase + t * 2048 + sw);
                acc[0][t] = __builtin_amdgcn_mfma_f32_16x16x32_bf16(af[p9][0][cib], bf, acc[0][t], 0, 0, 0);
                acc[1][t] = __builtin_amdgcn_mfma_f32_16x16x32_bf16(af[p9][1][cib], bf, acc[1][t], 0, 0, 0);
            }
        }
    }

    // epilogue: pure stores (residual folded into A)
    const int y = y0 + r;
    float* ob = out + (((size_t)b * COUT + cog * 32 + lg * 4) * HH + y) * WW + ln;
    #pragma unroll
    for (int ct = 0; ct < 2; ++ct)
        #pragma unroll
        for (int t = 0; t < 7; ++t)
            #pragma unroll
            for (int rg = 0; rg < 4; ++rg)
                ob[((size_t)(ct * 16 + rg)) * HH * WW + t * 16] = acc[ct][t][rg];
}

extern "C" void kernel_launch(void* const* d_in, const int* in_sizes, int n_in,
                              void* d_out, int out_size, void* d_ws, size_t ws_size,
                              hipStream_t stream) {
    const float* cls      = (const float*)d_in[0];
    const float* features = (const float*)d_in[1];
    const float* W1       = (const float*)d_in[2];
    const float* b1       = (const float*)d_in[3];
    const float* W2       = (const float*)d_in[4];
    const float* b2       = (const float*)d_in[5];
    float* out = (float*)d_out;

    float*          h  = (float*)d_ws;                       // 12 KB
    unsigned short* Ag = (unsigned short*)(h + BB * HID);    // 1.18 MB bf16 A[b][p9][co][ci]
    unsigned short* P  = Ag + (size_t)BB * 9 * 4096;         // 26.6 MB padded NHWC bf16

    pre_mlp1<<<HH * BB + 32 + 192, 256, 0, stream>>>(features, P, cls, W1, b1, h);
    mlp2_kernel<<<TOTAL / 64, 256, 0, stream>>>(h, W2, b2, Ag);
    conv_kernel<<<56 * BB, 256, 0, stream>>>(Ag, P, out);
}

// Round 11
// 59.757 us; speedup vs baseline: 1.0137x; 1.0137x over previous
//
#include <hip/hip_runtime.h>
#include <hip/hip_bf16.h>

#define BB   16
#define EMB  768
#define CIN  64
#define COUT 64
#define HH   112
#define WW   112
#define HID  192
#define TOTAL 36864                 // COUT*CIN*9
#define KSZ  576                    // CIN*9
#define PW   114                    // padded H/W
#define CELL 128                    // bytes per (row,col) cell: 64 ci * 2B
#define ROWB (PW * CELL)            // 14592 B per padded row
#define RING 6                      // LDS ring slots (rows)

typedef short bf16x8 __attribute__((ext_vector_type(8)));
typedef float f32x4  __attribute__((ext_vector_type(4)));
typedef int   i32x4  __attribute__((ext_vector_type(4)));

static __device__ __forceinline__ unsigned short f2bf(float f) {
    unsigned u = __float_as_uint(f);
    u += 0x7FFF + ((u >> 16) & 1);          // RNE
    return (unsigned short)(u >> 16);
}

static __device__ __forceinline__ bf16x8 pack8(const float* v) {
    bf16x8 r;
    #pragma unroll
    for (int j = 0; j < 8; ++j) r[j] = (short)f2bf(v[j]);
    return r;
}

#define GLOAD_LDS16(g, l) \
    __builtin_amdgcn_global_load_lds((const __attribute__((address_space(1))) void*)(g), \
                                     (__attribute__((address_space(3))) void*)(l), 16, 0, 0)

#define WAIT_VMCNT(n) do { asm volatile("s_waitcnt vmcnt(" #n ")" ::: "memory"); \
                           __builtin_amdgcn_sched_barrier(0); } while (0)

// ---- K1: prepass (blocks 0..1823) + mlp1 (blocks 1856..2047) ----
__global__ __launch_bounds__(256) void pre_mlp1(const float* __restrict__ feat,
                                                unsigned short* __restrict__ P,
                                                const float* __restrict__ cls,
                                                const float* __restrict__ W1,
                                                const float* __restrict__ b1,
                                                float* __restrict__ h) {
    __shared__ float smem[EMB + 16 * 17];
    const int bid = blockIdx.x;
    const int tid = threadIdx.x;

    if (bid < HH * BB) {
        // ---------------- prepass data row: in-register NCHW->NHWC bf16 ----------------
        const int b = bid & 15;
        const int y = bid >> 4;                 // image row 0..111
        unsigned short* Prow = P + ((size_t)b * PW + y + 1) * (PW * 64);
        if (tid < 16) {                         // zero x-halo cells 0 and 113
            const int cell = (tid >> 3) ? (PW - 1) : 0;
            *(i32x4*)((char*)Prow + cell * CELL + (tid & 7) * 16) = (i32x4){0, 0, 0, 0};
        }
        const int o = tid >> 5;                 // ci octet 0..7
        const int q = tid & 31;                 // px quad, active < 28
        if (q < 28) {
            const float* fb = feat + (((size_t)b * CIN + o * 8) * HH + y) * WW + 4 * q;
            f32x4 v[8];
            #pragma unroll
            for (int j = 0; j < 8; ++j) v[j] = *(const f32x4*)(fb + (size_t)j * (HH * WW));
            #pragma unroll
            for (int i = 0; i < 4; ++i) {
                unsigned short w[8];
                #pragma unroll
                for (int j = 0; j < 8; ++j) w[j] = f2bf(v[j][i]);
                *(bf16x8*)(Prow + (size_t)(4 * q + i + 1) * 64 + o * 8) = *(bf16x8*)w;
            }
        }
    } else if (bid < HH * BB + 32) {
        // ---------------- prepass halo rows (py = 0, 113) ----------------
        const int idx = bid - HH * BB;
        const int b = idx & 15;
        unsigned short* Prow = P + ((size_t)b * PW + ((idx >> 4) ? (PW - 1) : 0)) * (PW * 64);
        #pragma unroll
        for (int k = 0; k < 4; ++k) {
            const int i = tid + 256 * k;
            if (i < 912) ((i32x4*)Prow)[i] = (i32x4){0, 0, 0, 0};
        }
    } else {
        // ---------------- mlp1: h = relu(cls @ W1 + b1) ----------------
        float* xs  = smem;
        float* red = smem + EMB;
        const int idx = bid - (HH * BB + 32);   // 0..191
        const int b   = idx / 12;
        const int jg  = idx - 12 * b;
        for (int i = tid; i < EMB; i += 256) xs[i] = cls[b * EMB + i];
        __syncthreads();
        const int j16 = tid & 15;
        const int kq  = tid >> 4;
        const int j   = jg * 16 + j16;
        float acc = 0.f;
        #pragma unroll
        for (int k = kq * 48; k < kq * 48 + 48; ++k) acc += xs[k] * W1[k * HID + j];
        red[j16 * 17 + kq] = acc;
        __syncthreads();
        if (tid < 16) {
            float s = b1[jg * 16 + tid];
            #pragma unroll
            for (int q = 0; q < 16; ++q) s += red[tid * 17 + q];
            h[b * HID + jg * 16 + tid] = fmaxf(s, 0.f);
        }
    }
}

// ---- K2: MFMA GEMM  params = tanh(h @ W2 + b2) (+ identity at center tap) ----
__global__ __launch_bounds__(256) void mlp2_kernel(const float* __restrict__ h,
                                                   const float* __restrict__ W2,
                                                   const float* __restrict__ b2,
                                                   unsigned short* __restrict__ Ag) {
    __shared__ float hs[16 * 193];
    const int tid = threadIdx.x;
    for (int i = tid; i < BB * HID; i += 256) {
        const int bb = i / HID;
        hs[bb * 193 + (i - bb * HID)] = h[i];
    }
    __syncthreads();
    const int wave = tid >> 6;
    const int lane = tid & 63;
    const int lg   = lane >> 4;
    const int ln   = lane & 15;
    const int t0   = (blockIdx.x * 4 + wave) * 16;

    bf16x8 a6[6];
    #pragma unroll
    for (int kk = 0; kk < 6; ++kk) {
        float v[8];
        #pragma unroll
        for (int j = 0; j < 8; ++j) v[j] = hs[ln * 193 + kk * 32 + lg * 8 + j];
        a6[kk] = pack8(v);
    }

    f32x4 acc = (f32x4){0.f, 0.f, 0.f, 0.f};
    #pragma unroll
    for (int kk = 0; kk < 6; ++kk) {
        float w[8];
        #pragma unroll
        for (int j = 0; j < 8; ++j)
            w[j] = W2[(size_t)(kk * 32 + lg * 8 + j) * TOTAL + t0 + ln];
        acc = __builtin_amdgcn_mfma_f32_16x16x32_bf16(a6[kk], pack8(w), acc, 0, 0, 0);
    }

    const int t    = t0 + ln;
    const float bias = b2[t];
    const int co  = t / KSZ;
    const int rem = t - co * KSZ;
    const int ci  = rem / 9;
    const int p9  = rem - ci * 9;
    const float idv = (p9 == 4 && co == ci) ? 1.f : 0.f;
    unsigned short* pA = Ag + (size_t)(p9 * 64 + co) * 64 + ci;
    #pragma unroll
    for (int rg = 0; rg < 4; ++rg) {
        const int bi = lg * 4 + rg;
        pA[(size_t)bi * TOTAL] = f2bf(tanhf(acc[rg] + bias) + idv);
    }
}

// -------- K3: conv MFMA implicit GEMM, pipelined 4-tile block, 6-row LDS ring --------
// Grid 224 = 16b x 14 strips (8 rows). Block: 256 thr / 4 waves = (co-half, row).
// Ring: 6 padded rows x [cell][64ci] in dynamic LDS (87552 B), slot = local_row % 6.
// Pipeline: prologue stages rows 0-3 (drain); iter t: barrier, issue rows 2t+4/2t+5,
// compute tile t, stores. Cross-iter wait = vmcnt(56): 56 newer stores may fly,
// the 8 older stage-loads are retired (in-order retirement).
__global__ __launch_bounds__(256, 1) void conv_kernel(const unsigned short* __restrict__ Ag,
                                                      const unsigned short* __restrict__ P,
                                                      float* __restrict__ out) {
    extern __shared__ __align__(16) char lds[];     // RING * ROWB = 87552 B
    const int tid = threadIdx.x;
    // XCD-chunked swizzle: 28 consecutive logical blocks (= 2 batches) per XCD
    const int bid   = (blockIdx.x & 7) * 28 + (blockIdx.x >> 3);
    const int b     = bid / 14;
    const int strip = bid - b * 14;
    const int Y0    = strip * 8;

    const int wave = tid >> 6;
    const int lane = tid & 63;
    const int cog  = wave & 1;
    const int r    = wave >> 1;
    const int lg   = lane >> 4;
    const int ln   = lane & 15;

    // A-fragments: 32 co x 9 taps x 64 ci per wave, loaded ONCE, reused 4 tiles
    const unsigned short* Ab = Ag + (size_t)b * 9 * 4096;
    bf16x8 af[9][2][2];
    #pragma unroll
    for (int p9 = 0; p9 < 9; ++p9)
        #pragma unroll
        for (int ct = 0; ct < 2; ++ct)
            #pragma unroll
            for (int cib = 0; cib < 2; ++cib)
                af[p9][ct][cib] = *(const bf16x8*)(Ab + (size_t)(p9 * 64 + cog * 32 + ct * 16 + ln) * 64
                                                   + cib * 32 + lg * 8);

    const char* Pb = (const char*)P + ((size_t)b * PW + Y0) * ROWB;

    // prologue: stage local rows 0..3 into slots 0..3 (16 chunks/thread, 228 active)
    if (tid < 228) {
        #pragma unroll
        for (int k = 0; k < 16; ++k) {
            const int i = k * 228 + tid;            // 0..3647
            const int s = i / 912, jj = i - s * 912;
            const int c = jj >> 3, g = jj & 7;
            GLOAD_LDS16(Pb + (size_t)s * ROWB + c * CELL + ((g ^ (c & 7)) << 4),
                        lds + (size_t)i * 16);
        }
    }
    WAIT_VMCNT(0);
    __builtin_amdgcn_s_barrier();
    __builtin_amdgcn_sched_barrier(0);

    #pragma unroll
    for (int t = 0; t < 4; ++t) {
        if (t > 0) {
            WAIT_VMCNT(56);                          // drains S_{t+1}; stores keep flying
            __builtin_amdgcn_s_barrier();
            __builtin_amdgcn_sched_barrier(0);
        }
        if (t < 3) {                                 // issue S_{t+2}: local rows 2t+4, 2t+5
            const int lr0 = 2 * t + 4;
            const int s0  = lr0 % RING;              // 4, 0, 2 — slot pair contiguous
            const char* Ps = Pb + (size_t)lr0 * ROWB;
            char* ldst = lds + (size_t)s0 * ROWB;
            if (tid < 228) {
                #pragma unroll
                for (int k = 0; k < 8; ++k) {
                    const int i = k * 228 + tid;     // 0..1823
                    const int s = i / 912, jj = i - s * 912;
                    const int c = jj >> 3, g = jj & 7;
                    GLOAD_LDS16(Ps + (size_t)s * ROWB + c * CELL + ((g ^ (c & 7)) << 4),
                                ldst + (size_t)i * 16);
                }
            }
        }

        // row pointers for this wave's 3 taps
        const char* rp[3];
        #pragma unroll
        for (int kh = 0; kh < 3; ++kh) {
            const int lr = 2 * t + r + kh;
            const int sl = lr - (lr >= RING ? RING : 0);
            rp[kh] = lds + (size_t)sl * ROWB;
        }

        f32x4 acc[2][7];
        #pragma unroll
        for (int ct = 0; ct < 2; ++ct)
            #pragma unroll
            for (int tt = 0; tt < 7; ++tt) acc[ct][tt] = (f32x4){0.f, 0.f, 0.f, 0.f};

        #pragma unroll
        for (int p9 = 0; p9 < 9; ++p9) {
            const int kh = p9 / 3, kw = p9 - 3 * kh;
            const char* lbase = rp[kh] + (ln + kw) * CELL;
            const int   c7    = (ln + kw) & 7;
            #pragma unroll
            for (int cib = 0; cib < 2; ++cib) {
                const int sw = ((cib * 4 + lg) ^ c7) << 4;
                #pragma unroll
                for (int tt = 0; tt < 7; ++tt) {
                    const bf16x8 bf = *(const bf16x8*)(lbase + tt * (16 * CELL) + sw);
                    acc[0][tt] = __builtin_amdgcn_mfma_f32_16x16x32_bf16(af[p9][0][cib], bf, acc[0][tt], 0, 0, 0);
                    acc[1][tt] = __builtin_amdgcn_mfma_f32_16x16x32_bf16(af[p9][1][cib], bf, acc[1][tt], 0, 0, 0);
                }
            }
        }

        // stores (residual folded into A); fly across the next barrier
        const int y = Y0 + 2 * t + r;
        float* ob = out + (((size_t)b * COUT + cog * 32 + lg * 4) * HH + y) * WW + ln;
        #pragma unroll
        for (int ct = 0; ct < 2; ++ct)
            #pragma unroll
            for (int tt = 0; tt < 7; ++tt)
                #pragma unroll
                for (int rg = 0; rg < 4; ++rg)
                    ob[((size_t)(ct * 16 + rg)) * HH * WW + tt * 16] = acc[ct][tt][rg];
    }
}

extern "C" void kernel_launch(void* const* d_in, const int* in_sizes, int n_in,
                              void* d_out, int out_size, void* d_ws, size_t ws_size,
                              hipStream_t stream) {
    const float* cls      = (const float*)d_in[0];
    const float* features = (const float*)d_in[1];
    const float* W1       = (const float*)d_in[2];
    const float* b1       = (const float*)d_in[3];
    const float* W2       = (const float*)d_in[4];
    const float* b2       = (const float*)d_in[5];
    float* out = (float*)d_out;

    float*          h  = (float*)d_ws;                       // 12 KB
    unsigned short* Ag = (unsigned short*)(h + BB * HID);    // 1.18 MB bf16 A[b][p9][co][ci]
    unsigned short* P  = Ag + (size_t)BB * 9 * 4096;         // 26.6 MB padded NHWC bf16

    (void)hipFuncSetAttribute((const void*)conv_kernel,
                              hipFuncAttributeMaxDynamicSharedMemorySize, RING * ROWB);

    pre_mlp1<<<HH * BB + 32 + 192, 256, 0, stream>>>(features, P, cls, W1, b1, h);
    mlp2_kernel<<<TOTAL / 64, 256, 0, stream>>>(h, W2, b2, Ag);
    conv_kernel<<<224, 256, RING * ROWB, stream>>>(Ag, P, out);
}